// Round 4
// baseline (217.569 us; speedup 1.0000x reference)
//
#include <hip/hip_runtime.h>

typedef unsigned short u16;
typedef unsigned int   u32;
typedef float f32x4  __attribute__((ext_vector_type(4)));
typedef float f32x16 __attribute__((ext_vector_type(16)));
typedef __bf16 bf16x8 __attribute__((ext_vector_type(8)));

__device__ __forceinline__ u16 f2bf(float f){
  u32 u = __float_as_uint(f);
  u += 0x7fffu + ((u >> 16) & 1u);          // RNE
  return (u16)(u >> 16);
}

// async global->LDS, 16B per lane; LDS dest is wave-uniform base + lane*16
__device__ __forceinline__ void gld16(const void* g, void* l){
  __builtin_amdgcn_global_load_lds((const __attribute__((address_space(1))) u32*)g,
                                   (__attribute__((address_space(3))) u32*)l, 16, 0, 0);
}

// ---------------- weight conversion: fp32->bf16, sigs->ternary bf16 ----------------
__global__ __launch_bounds__(256) void convert_kernel(
    const float* __restrict__ qw, const float* __restrict__ ow,
    const float* __restrict__ sg,
    u16* __restrict__ qwb, u16* __restrict__ owb, u16* __restrict__ sgb){
  int i = blockIdx.x * 256 + threadIdx.x;   // 1,048,576 elements each
  qwb[i] = f2bf(qw[i]);
  owb[i] = f2bf(ow[i]);
  float s = sg[i];
  float t = (s > 0.3f) ? 1.0f : ((s < -0.3f) ? -1.0f : 0.0f);
  sgb[i] = f2bf(t);                          // {-1,0,1} exact in bf16
}

// ---------------- LayerNorm: one block per token ----------------
__global__ __launch_bounds__(256) void ln_kernel(
    const float* __restrict__ x, const float* __restrict__ g,
    const float* __restrict__ b, u16* __restrict__ xn){
  const int t = blockIdx.x, tid = threadIdx.x;
  f32x4 v = *(const f32x4*)(x + (size_t)t * 1024 + tid * 4);
  float s  = v[0] + v[1] + v[2] + v[3];
  float ss = v[0]*v[0] + v[1]*v[1] + v[2]*v[2] + v[3]*v[3];
  for (int off = 32; off; off >>= 1){
    s  += __shfl_down(s, off);
    ss += __shfl_down(ss, off);
  }
  __shared__ float red[8];
  int w = tid >> 6;
  if ((tid & 63) == 0){ red[w] = s; red[4 + w] = ss; }
  __syncthreads();
  s  = red[0] + red[1] + red[2] + red[3];
  ss = red[4] + red[5] + red[6] + red[7];
  float mean = s * (1.0f / 1024.0f);
  float var  = ss * (1.0f / 1024.0f) - mean * mean;   // jnp.var (ddof=0)
  float rs   = rsqrtf(var + 1e-5f);
  f32x4 gv = *(const f32x4*)(g + tid * 4);
  f32x4 bv = *(const f32x4*)(b + tid * 4);
  float y0 = (v[0]-mean)*rs*gv[0]+bv[0];
  float y1 = (v[1]-mean)*rs*gv[1]+bv[1];
  float y2 = (v[2]-mean)*rs*gv[2]+bv[2];
  float y3 = (v[3]-mean)*rs*gv[3]+bv[3];
  uint2 pk;
  pk.x = (u32)f2bf(y0) | ((u32)f2bf(y1) << 16);
  pk.y = (u32)f2bf(y2) | ((u32)f2bf(y3) << 16);
  *(uint2*)(xn + (size_t)t * 1024 + tid * 4) = pk;
}

// ---------------- bf16 MFMA GEMM: C[m,n] = sum_k A[m,k]*B[n,k] (+epilogue) ----------------
// M=8192, N=1024, K=1024. 128x128 tile, 4 waves in 2x2, each wave 64x64 (4x4 MFMA 16x16x32).
// LDS unpadded 64-u16 stride, XOR-swizzled: chunk g (16B) of row s lives at position g^(s&7).
// Staged via global_load_lds (lane-linear dest); swizzle applied on the SOURCE address.
// mode 0: outb[m,n] = bf16(C + bias[n]);  mode 1: outf[m,n] = C + bias[n] + resid[m,n]
__global__ __launch_bounds__(256, 3) void gemm_bt(
    const u16* __restrict__ A, const u16* __restrict__ B,
    const float* __restrict__ bias, const float* __restrict__ resid,
    float* __restrict__ outf, u16* __restrict__ outb, int mode){
  __shared__ u16 As[128 * 64];      // 16 KB
  __shared__ u16 Bs[128 * 64];
  const int tid = threadIdx.x;
  const int m0 = blockIdx.y * 128, n0 = blockIdx.x * 128;
  const int w = tid >> 6, lane = tid & 63, lm = lane & 15, quad = lane >> 4;
  const int wm = (w & 1) * 64, wn = (w >> 1) * 64;
  const int lr = lane >> 3;                 // row-within-8 of this lane's staging chunk
  const int lg = (lane & 7) ^ lr;           // swizzled source chunk id
  const f32x4 fz = {0.f, 0.f, 0.f, 0.f};
  f32x4 acc[4][4];
  #pragma unroll
  for (int i = 0; i < 4; ++i)
    #pragma unroll
    for (int j = 0; j < 4; ++j) acc[i][j] = fz;

  const u16* gA = A + (size_t)(m0 + w * 32 + lr) * 1024 + lg * 8;
  const u16* gB = B + (size_t)(n0 + w * 32 + lr) * 1024 + lg * 8;
  u16* lA = &As[(w * 32) * 64];             // wave-uniform LDS bases
  u16* lB = &Bs[(w * 32) * 64];
  const int sw = lm & 7;

  for (int kt = 0; kt < 16; ++kt){
    #pragma unroll
    for (int sub = 0; sub < 4; ++sub){
      gld16(gA + (size_t)(sub * 8) * 1024 + kt * 64, lA + sub * 8 * 64);
      gld16(gB + (size_t)(sub * 8) * 1024 + kt * 64, lB + sub * 8 * 64);
    }
    __syncthreads();
    #pragma unroll
    for (int kk = 0; kk < 2; ++kk){
      const int ch = ((quad + kk * 4) ^ sw) * 8;   // swizzled chunk offset (u16)
      bf16x8 afr[4], bfr[4];
      #pragma unroll
      for (int i = 0; i < 4; ++i)
        afr[i] = *(const bf16x8*)(&As[(wm + i * 16 + lm) * 64 + ch]);
      #pragma unroll
      for (int j = 0; j < 4; ++j)
        bfr[j] = *(const bf16x8*)(&Bs[(wn + j * 16 + lm) * 64 + ch]);
      #pragma unroll
      for (int i = 0; i < 4; ++i)
        #pragma unroll
        for (int j = 0; j < 4; ++j)
          acc[i][j] = __builtin_amdgcn_mfma_f32_16x16x32_bf16(afr[i], bfr[j], acc[i][j], 0, 0, 0);
    }
    __syncthreads();
  }

  #pragma unroll
  for (int i = 0; i < 4; ++i){
    #pragma unroll
    for (int r = 0; r < 4; ++r){
      int grow = m0 + wm + i * 16 + quad * 4 + r;
      #pragma unroll
      for (int j = 0; j < 4; ++j){
        int gcol = n0 + wn + j * 16 + lm;
        float v = acc[i][j][r] + bias[gcol];
        if (mode){
          v += resid[(size_t)grow * 1024 + gcol];
          outf[(size_t)grow * 1024 + gcol] = v;
        } else {
          outb[(size_t)grow * 1024 + gcol] = f2bf(v);
        }
      }
    }
  }
}

// ---------------- fused scores + top2 + softmax + gather ----------------
// block = 128 tokens x 1 head; 4 waves, wave w owns tokens [w*32, w*32+32).
// 32x32x16 MFMA: per wave-iteration 1024 scores from 4 MFMAs.
// Top-2 via key packing: slot index lives in the low 10 mantissa bits of the
// fp32 score (<=2^-13 relative perturbation); update = and_or + max + med3.
// sig tile (128 slots, 16KB) double-buffered in LDS, XOR-swizzled.
// __launch_bounds__(256,4): 128-reg cap so v1/v2/acc live in ARCH VGPRs —
// at 60 regs (R3) the compiler parked them in AGPRs and every fmax/fmed3
// grew accvgpr_read/write pairs (~3x VALU inst bloat).
__global__ __launch_bounds__(256, 4) void route_kernel(
    const u16* __restrict__ q, const u16* __restrict__ sig,
    const float* __restrict__ V, const float* __restrict__ temp,
    u16* __restrict__ rd){
  const int h = blockIdx.y;
  const int t0 = blockIdx.x * 128;
  const int tid = threadIdx.x, w = tid >> 6, lane = tid & 63;
  const int col = lane & 31, half = lane >> 5;

  __shared__ u16 sbuf[2][128 * 64];         // 2 x 16 KB, swizzled
  __shared__ float fw1[128], fw2[128];
  __shared__ int   fi1[128], fi2[128];

  // A fragments: token m = t0 + w*32 + col; chunk c holds k = c*16 + half*8 + j
  const u16* qrow = q + (size_t)(t0 + w * 32 + col) * 1024 + h * 64 + half * 8;
  bf16x8 afr[4];
  #pragma unroll
  for (int c = 0; c < 4; ++c) afr[c] = *(const bf16x8*)(qrow + c * 16);

  const u16* sigh = sig + (size_t)h * 65536;

  // staging: wave w stages rows [w*32, w*32+32) of the 128-slot tile.
  // 8 lanes per row (16B chunks); swizzle: LDS pos p of row s holds chunk p^(s&7).
  const int lr = lane >> 3, lg = (lane & 7) ^ lr;
  const u16* ssrc = sigh + (size_t)(w * 32 + lr) * 64 + lg * 8;
  auto stage = [&](int t, int b){
    const u16* s0 = ssrc + (size_t)t * 128 * 64;
    u16* d0 = &sbuf[b][(w * 32) * 64];
    #pragma unroll
    for (int sub = 0; sub < 4; ++sub)
      gld16(s0 + sub * 8 * 64, d0 + sub * 8 * 64);
  };

  // loop-invariant swizzled read offsets (u16 units): chunk c2 = c*2+half of row col
  int p0 = ((0 + half) ^ (col & 7)) * 8;
  int p1 = ((2 + half) ^ (col & 7)) * 8;
  int p2 = ((4 + half) ^ (col & 7)) * 8;
  int p3 = ((6 + half) ^ (col & 7)) * 8;

  const f32x16 fzero = {};                   // loop-invariant MFMA C=0 operand
  float v1[16], v2[16];
  #pragma unroll
  for (int r = 0; r < 16; ++r){ v1[r] = -3.0e38f; v2[r] = -3.0e38f; }

  stage(0, 0);
  for (int t = 0; t < 8; ++t){
    __syncthreads();                         // drains vmcnt: staging of buf t&1 visible
    if (t < 7) stage(t + 1, (t + 1) & 1);
    const u16* buf = sbuf[t & 1];
    #pragma unroll
    for (int sbl = 0; sbl < 4; ++sbl){
      const u16* srow = &buf[(sbl * 32 + col) * 64];
      bf16x8 b0 = *(const bf16x8*)(srow + p0);
      bf16x8 b1 = *(const bf16x8*)(srow + p1);
      bf16x8 b2 = *(const bf16x8*)(srow + p2);
      bf16x8 b3 = *(const bf16x8*)(srow + p3);
      f32x16 acc;
      acc = __builtin_amdgcn_mfma_f32_32x32x16_bf16(afr[0], b0, fzero, 0, 0, 0);
      acc = __builtin_amdgcn_mfma_f32_32x32x16_bf16(afr[1], b1, acc, 0, 0, 0);
      acc = __builtin_amdgcn_mfma_f32_32x32x16_bf16(afr[2], b2, acc, 0, 0, 0);
      acc = __builtin_amdgcn_mfma_f32_32x32x16_bf16(afr[3], b3, acc, 0, 0, 0);
      u32 sidx = (u32)(t * 128 + sbl * 32 + col);
      #pragma unroll
      for (int r = 0; r < 16; ++r){
        u32 u = __float_as_uint(acc[r]);
        float key = __uint_as_float((u & 0xFFFFFC00u) | sidx);
        float o1 = v1[r];
        v1[r] = fmaxf(o1, key);
        v2[r] = __builtin_amdgcn_fmed3f(o1, v2[r], key);
      }
    }
  }

  // butterfly merge across the 32 cols (each lane-group holds same 16 token rows)
  #pragma unroll
  for (int off = 1; off < 32; off <<= 1){
    #pragma unroll
    for (int r = 0; r < 16; ++r){
      float b1v = __shfl_xor(v1[r], off);
      float b2v = __shfl_xor(v2[r], off);
      float a1 = v1[r];
      v1[r] = fmaxf(a1, b1v);
      v2[r] = __builtin_amdgcn_fmed3f(a1, b1v, fmaxf(v2[r], b2v));
    }
  }

  if (col == 0){                             // lanes 0 and 32 of each wave
    float tsc = 1.0f / (temp[0] * 8.0f);     // 1/(temperature*sqrt(64))
    #pragma unroll
    for (int r = 0; r < 16; ++r){
      int row = (r & 3) + 8 * (r >> 2) + 4 * half;   // verified 32x32 C/D row map
      int tl = w * 32 + row;
      u32 u1 = __float_as_uint(v1[r]);
      u32 u2 = __float_as_uint(v2[r]);
      float s1 = __uint_as_float(u1 & 0xFFFFFC00u);
      float s2 = __uint_as_float(u2 & 0xFFFFFC00u);
      float ex = __expf((s2 - s1) * tsc);    // <= 1, stable
      float iw = 1.0f / (1.0f + ex);
      fw1[tl] = iw; fw2[tl] = ex * iw;
      fi1[tl] = (int)(u1 & 1023u); fi2[tl] = (int)(u2 & 1023u);
    }
  }
  __syncthreads();

  // gather: token = tid>>1, dims [(tid&1)*32, +32)
  int tl = tid >> 1, d0 = (tid & 1) * 32;
  const float* va = V + ((size_t)h * 1024 + fi1[tl]) * 64 + d0;
  const float* vb = V + ((size_t)h * 1024 + fi2[tl]) * 64 + d0;
  float W1 = fw1[tl], W2 = fw2[tl];
  u16* dst = rd + (size_t)(t0 + tl) * 1024 + h * 64 + d0;
  #pragma unroll
  for (int g = 0; g < 4; ++g){
    f32x4 xa = *(const f32x4*)(va + g * 8);
    f32x4 xb = *(const f32x4*)(va + g * 8 + 4);
    f32x4 ya = *(const f32x4*)(vb + g * 8);
    f32x4 yb = *(const f32x4*)(vb + g * 8 + 4);
    uint4 o;
    o.x = (u32)f2bf(W1*xa[0]+W2*ya[0]) | ((u32)f2bf(W1*xa[1]+W2*ya[1]) << 16);
    o.y = (u32)f2bf(W1*xa[2]+W2*ya[2]) | ((u32)f2bf(W1*xa[3]+W2*ya[3]) << 16);
    o.z = (u32)f2bf(W1*xb[0]+W2*yb[0]) | ((u32)f2bf(W1*xb[1]+W2*yb[1]) << 16);
    o.w = (u32)f2bf(W1*xb[2]+W2*yb[2]) | ((u32)f2bf(W1*xb[3]+W2*yb[3]) << 16);
    *(uint4*)(dst + g * 8) = o;
  }
}

extern "C" void kernel_launch(void* const* d_in, const int* in_sizes, int n_in,
                              void* d_out, int out_size, void* d_ws, size_t ws_size,
                              hipStream_t stream){
  const float* x    = (const float*)d_in[0];
  const float* lng  = (const float*)d_in[1];
  const float* lnb  = (const float*)d_in[2];
  const float* qw   = (const float*)d_in[3];
  const float* qb   = (const float*)d_in[4];
  const float* sig  = (const float*)d_in[5];
  const float* sv   = (const float*)d_in[6];
  const float* ow   = (const float*)d_in[7];
  const float* ob   = (const float*)d_in[8];
  const float* temp = (const float*)d_in[9];
  float* out = (float*)d_out;

  char* ws = (char*)d_ws;
  u16* xn   = (u16*)(ws);                                  // 16 MiB  (x_norm bf16; reused as `read`)
  u16* qwb  = (u16*)(ws + 16777216);                       //  2 MiB
  u16* owb  = (u16*)(ws + 16777216 + 2097152);             //  2 MiB
  u16* sgb  = (u16*)(ws + 16777216 + 2 * 2097152);         //  2 MiB
  u16* qb16 = (u16*)(ws + 16777216 + 3 * 2097152);         // 16 MiB  (q bf16)
  u16* rdb  = xn;                                          // alias: x_norm dead after GEMM1

  convert_kernel<<<4096, 256, 0, stream>>>(qw, ow, sig, qwb, owb, sgb);
  ln_kernel<<<8192, 256, 0, stream>>>(x, lng, lnb, xn);
  gemm_bt<<<dim3(8, 64), 256, 0, stream>>>(xn, qwb, qb, nullptr, nullptr, qb16, 0);
  route_kernel<<<dim3(64, 16), 256, 0, stream>>>(qb16, sgb, sv, temp, rdb);
  gemm_bt<<<dim3(8, 64), 256, 0, stream>>>(rdb, owb, ob, x, out, nullptr, 1);
}

// Round 5
// 217.425 us; speedup vs baseline: 1.0007x; 1.0007x over previous
//
#include <hip/hip_runtime.h>

typedef unsigned short u16;
typedef unsigned int   u32;
typedef float f32x4  __attribute__((ext_vector_type(4)));
typedef float f32x16 __attribute__((ext_vector_type(16)));
typedef __bf16 bf16x8 __attribute__((ext_vector_type(8)));

__device__ __forceinline__ u16 f2bf(float f){
  u32 u = __float_as_uint(f);
  u += 0x7fffu + ((u >> 16) & 1u);          // RNE
  return (u16)(u >> 16);
}

// async global->LDS, 16B per lane; LDS dest is wave-uniform base + lane*16
__device__ __forceinline__ void gld16(const void* g, void* l){
  __builtin_amdgcn_global_load_lds((const __attribute__((address_space(1))) u32*)g,
                                   (__attribute__((address_space(3))) u32*)l, 16, 0, 0);
}

// ---------------- weight conversion: fp32->bf16, sigs->ternary bf16 ----------------
__global__ __launch_bounds__(256) void convert_kernel(
    const float* __restrict__ qw, const float* __restrict__ ow,
    const float* __restrict__ sg,
    u16* __restrict__ qwb, u16* __restrict__ owb, u16* __restrict__ sgb){
  int i = blockIdx.x * 256 + threadIdx.x;   // 1,048,576 elements each
  qwb[i] = f2bf(qw[i]);
  owb[i] = f2bf(ow[i]);
  float s = sg[i];
  float t = (s > 0.3f) ? 1.0f : ((s < -0.3f) ? -1.0f : 0.0f);
  sgb[i] = f2bf(t);                          // {-1,0,1} exact in bf16
}

// ---------------- LayerNorm: one block per token ----------------
__global__ __launch_bounds__(256) void ln_kernel(
    const float* __restrict__ x, const float* __restrict__ g,
    const float* __restrict__ b, u16* __restrict__ xn){
  const int t = blockIdx.x, tid = threadIdx.x;
  f32x4 v = *(const f32x4*)(x + (size_t)t * 1024 + tid * 4);
  float s  = v[0] + v[1] + v[2] + v[3];
  float ss = v[0]*v[0] + v[1]*v[1] + v[2]*v[2] + v[3]*v[3];
  for (int off = 32; off; off >>= 1){
    s  += __shfl_down(s, off);
    ss += __shfl_down(ss, off);
  }
  __shared__ float red[8];
  int w = tid >> 6;
  if ((tid & 63) == 0){ red[w] = s; red[4 + w] = ss; }
  __syncthreads();
  s  = red[0] + red[1] + red[2] + red[3];
  ss = red[4] + red[5] + red[6] + red[7];
  float mean = s * (1.0f / 1024.0f);
  float var  = ss * (1.0f / 1024.0f) - mean * mean;   // jnp.var (ddof=0)
  float rs   = rsqrtf(var + 1e-5f);
  f32x4 gv = *(const f32x4*)(g + tid * 4);
  f32x4 bv = *(const f32x4*)(b + tid * 4);
  float y0 = (v[0]-mean)*rs*gv[0]+bv[0];
  float y1 = (v[1]-mean)*rs*gv[1]+bv[1];
  float y2 = (v[2]-mean)*rs*gv[2]+bv[2];
  float y3 = (v[3]-mean)*rs*gv[3]+bv[3];
  uint2 pk;
  pk.x = (u32)f2bf(y0) | ((u32)f2bf(y1) << 16);
  pk.y = (u32)f2bf(y2) | ((u32)f2bf(y3) << 16);
  *(uint2*)(xn + (size_t)t * 1024 + tid * 4) = pk;
}

// ---------------- bf16 MFMA GEMM: C[m,n] = sum_k A[m,k]*B[n,k] (+epilogue) ----------------
// M=8192, N=1024, K=1024. 128x128 tile, 4 waves in 2x2, each wave 64x64 (4x4 MFMA 16x16x32).
// Grid = 512 1-D, XCD-swizzled: XCD (b%8) owns a contiguous 1024-row A-stripe
// (2MB) + streams all of B (2MB) -> 4MB L2 working set/XCD; A fetched once
// device-wide (old 2-D grid made every XCD fetch all 16MB of A).
// LDS unpadded 64-u16 stride, XOR-swizzled: chunk g (16B) of row s at pos g^(s&7).
// mode 0: outb[m,n] = bf16(C + bias[n]);  mode 1: outf[m,n] = C + bias[n] + resid[m,n]
__global__ __launch_bounds__(256, 3) void gemm_bt(
    const u16* __restrict__ A, const u16* __restrict__ B,
    const float* __restrict__ bias, const float* __restrict__ resid,
    float* __restrict__ outf, u16* __restrict__ outb, int mode){
  __shared__ u16 As[128 * 64];      // 16 KB
  __shared__ u16 Bs[128 * 64];
  const int tid = threadIdx.x;
  const int b = blockIdx.x;
  const int m0 = ((b & 7) * 8 + ((b >> 3) & 7)) * 128;   // XCD-contiguous m-stripe
  const int n0 = (b >> 6) * 128;
  const int w = tid >> 6, lane = tid & 63, lm = lane & 15, quad = lane >> 4;
  const int wm = (w & 1) * 64, wn = (w >> 1) * 64;
  const int lr = lane >> 3;                 // row-within-8 of this lane's staging chunk
  const int lg = (lane & 7) ^ lr;           // swizzled source chunk id
  const f32x4 fz = {0.f, 0.f, 0.f, 0.f};
  f32x4 acc[4][4];
  #pragma unroll
  for (int i = 0; i < 4; ++i)
    #pragma unroll
    for (int j = 0; j < 4; ++j) acc[i][j] = fz;

  const u16* gA = A + (size_t)(m0 + w * 32 + lr) * 1024 + lg * 8;
  const u16* gB = B + (size_t)(n0 + w * 32 + lr) * 1024 + lg * 8;
  u16* lA = &As[(w * 32) * 64];             // wave-uniform LDS bases
  u16* lB = &Bs[(w * 32) * 64];
  const int sw = lm & 7;

  for (int kt = 0; kt < 16; ++kt){
    #pragma unroll
    for (int sub = 0; sub < 4; ++sub){
      gld16(gA + (size_t)(sub * 8) * 1024 + kt * 64, lA + sub * 8 * 64);
      gld16(gB + (size_t)(sub * 8) * 1024 + kt * 64, lB + sub * 8 * 64);
    }
    __syncthreads();
    #pragma unroll
    for (int kk = 0; kk < 2; ++kk){
      const int ch = ((quad + kk * 4) ^ sw) * 8;   // swizzled chunk offset (u16)
      bf16x8 afr[4], bfr[4];
      #pragma unroll
      for (int i = 0; i < 4; ++i)
        afr[i] = *(const bf16x8*)(&As[(wm + i * 16 + lm) * 64 + ch]);
      #pragma unroll
      for (int j = 0; j < 4; ++j)
        bfr[j] = *(const bf16x8*)(&Bs[(wn + j * 16 + lm) * 64 + ch]);
      #pragma unroll
      for (int i = 0; i < 4; ++i)
        #pragma unroll
        for (int j = 0; j < 4; ++j)
          acc[i][j] = __builtin_amdgcn_mfma_f32_16x16x32_bf16(afr[i], bfr[j], acc[i][j], 0, 0, 0);
    }
    __syncthreads();
  }

  #pragma unroll
  for (int i = 0; i < 4; ++i){
    #pragma unroll
    for (int r = 0; r < 4; ++r){
      int grow = m0 + wm + i * 16 + quad * 4 + r;
      #pragma unroll
      for (int j = 0; j < 4; ++j){
        int gcol = n0 + wn + j * 16 + lm;
        float v = acc[i][j][r] + bias[gcol];
        if (mode){
          v += resid[(size_t)grow * 1024 + gcol];
          outf[(size_t)grow * 1024 + gcol] = v;
        } else {
          outb[(size_t)grow * 1024 + gcol] = f2bf(v);
        }
      }
    }
  }
}

// distributed top-2 butterfly merge round: partner = col^O, keep half the rows
template<int O, int L>
__device__ __forceinline__ void merge_round(float* v1, float* v2, int col){
  float t1[L], t2[L];
  #pragma unroll
  for (int i = 0; i < L; ++i){ t1[i] = __shfl_xor(v1[i], O); t2[i] = __shfl_xor(v2[i], O); }
  if constexpr (L > 1){
    const int s = (col & O) ? L / 2 : 0;
    #pragma unroll
    for (int i = 0; i < L / 2; ++i){
      float m1 = v1[s + i], m2 = v2[s + i], o1 = t1[s + i], o2 = t2[s + i];
      v1[i] = fmaxf(m1, o1);
      v2[i] = __builtin_amdgcn_fmed3f(m1, o1, fmaxf(m2, o2));
    }
  } else {
    float m1 = v1[0];
    v1[0] = fmaxf(m1, t1[0]);
    v2[0] = __builtin_amdgcn_fmed3f(m1, t1[0], fmaxf(v2[0], t2[0]));
  }
}

// ---------------- fused scores + top2 + softmax + gather ----------------
// block = 128 tokens x 1 head; 4 waves, wave w owns tokens [w*32, w*32+32).
// 32x32x16 MFMA: 1024 scores per 4 MFMAs. Top-2 via key packing (index in the
// low 10 mantissa bits, <=2^-13 rel perturbation): and_or + max + med3 per score.
// sig tile (128 slots, 16KB) double-buffered in LDS, XOR-swizzled.
// amdgpu_waves_per_eu(2,4): min=2 -> 256-reg allocator budget so the arch/acc
// split still leaves v1/v2/acc/afr in ARCH VGPRs (R3/R4: 56-60 arch VGPRs ->
// state in AGPRs -> accvgpr_read/write around every fmax/fmed3, ~3-4x VALU bloat).
__global__ __launch_bounds__(256) __attribute__((amdgpu_waves_per_eu(2, 4)))
void route_kernel(
    const u16* __restrict__ q, const u16* __restrict__ sig,
    const float* __restrict__ V, const float* __restrict__ temp,
    u16* __restrict__ rd){
  const int h = blockIdx.y;
  const int t0 = blockIdx.x * 128;
  const int tid = threadIdx.x, w = tid >> 6, lane = tid & 63;
  const int col = lane & 31, half = lane >> 5;

  __shared__ u16 sbuf[2][128 * 64];         // 2 x 16 KB, swizzled
  __shared__ float fw1[128], fw2[128];
  __shared__ int   fi1[128], fi2[128];

  // A fragments: token m = t0 + w*32 + col; chunk c holds k = c*16 + half*8 + j
  const u16* qrow = q + (size_t)(t0 + w * 32 + col) * 1024 + h * 64 + half * 8;
  bf16x8 afr[4];
  #pragma unroll
  for (int c = 0; c < 4; ++c) afr[c] = *(const bf16x8*)(qrow + c * 16);

  const u16* sigh = sig + (size_t)h * 65536;

  // staging: wave w stages rows [w*32, w*32+32) of the 128-slot tile.
  // 8 lanes per row (16B chunks); swizzle: LDS pos p of row s holds chunk p^(s&7).
  const int lr = lane >> 3, lg = (lane & 7) ^ lr;
  const u16* ssrc = sigh + (size_t)(w * 32 + lr) * 64 + lg * 8;
  auto stage = [&](int t, int bb){
    const u16* s0 = ssrc + (size_t)t * 128 * 64;
    u16* d0 = &sbuf[bb][(w * 32) * 64];
    #pragma unroll
    for (int sub = 0; sub < 4; ++sub)
      gld16(s0 + sub * 8 * 64, d0 + sub * 8 * 64);
  };

  // loop-invariant swizzled read offsets (u16 units): chunk c2 = c*2+half of row col
  int p0 = ((0 + half) ^ (col & 7)) * 8;
  int p1 = ((2 + half) ^ (col & 7)) * 8;
  int p2 = ((4 + half) ^ (col & 7)) * 8;
  int p3 = ((6 + half) ^ (col & 7)) * 8;

  const f32x16 fzero = {};                   // loop-invariant MFMA C=0 operand
  float v1[16], v2[16];
  #pragma unroll
  for (int r = 0; r < 16; ++r){ v1[r] = -3.0e38f; v2[r] = -3.0e38f; }

  stage(0, 0);
  for (int t = 0; t < 8; ++t){
    __syncthreads();                         // drains vmcnt: staging of buf t&1 visible
    if (t < 7) stage(t + 1, (t + 1) & 1);
    const u16* buf = sbuf[t & 1];
    #pragma unroll
    for (int sbl = 0; sbl < 4; ++sbl){
      const u16* srow = &buf[(sbl * 32 + col) * 64];
      bf16x8 b0 = *(const bf16x8*)(srow + p0);
      bf16x8 b1 = *(const bf16x8*)(srow + p1);
      bf16x8 b2 = *(const bf16x8*)(srow + p2);
      bf16x8 b3 = *(const bf16x8*)(srow + p3);
      f32x16 acc;
      acc = __builtin_amdgcn_mfma_f32_32x32x16_bf16(afr[0], b0, fzero, 0, 0, 0);
      acc = __builtin_amdgcn_mfma_f32_32x32x16_bf16(afr[1], b1, acc, 0, 0, 0);
      acc = __builtin_amdgcn_mfma_f32_32x32x16_bf16(afr[2], b2, acc, 0, 0, 0);
      acc = __builtin_amdgcn_mfma_f32_32x32x16_bf16(afr[3], b3, acc, 0, 0, 0);
      u32 sidx = (u32)(t * 128 + sbl * 32 + col);
      #pragma unroll
      for (int r = 0; r < 16; ++r){
        u32 u = __float_as_uint(acc[r]);
        float key = __uint_as_float((u & 0xFFFFFC00u) | sidx);
        float o1 = v1[r];
        v1[r] = fmaxf(o1, key);
        v2[r] = __builtin_amdgcn_fmed3f(o1, v2[r], key);
      }
    }
  }

  // distributed butterfly: halve rows per round; lane pair (col, col^1) ends
  // owning row r=(col>>1)&15. 62 swizzles total (was 160) and no 32x redundancy.
  merge_round<16, 16>(v1, v2, col);
  merge_round< 8,  8>(v1, v2, col);
  merge_round< 4,  4>(v1, v2, col);
  merge_round< 2,  2>(v1, v2, col);
  merge_round< 1,  1>(v1, v2, col);

  float tsc = 1.0f / (temp[0] * 8.0f);       // 1/(temperature*sqrt(64))
  if ((col & 1) == 0){
    int r = (col >> 1) & 15;
    int row = (r & 3) + 8 * (r >> 2) + 4 * half;   // verified 32x32 C/D row map
    int tl = w * 32 + row;
    u32 u1 = __float_as_uint(v1[0]);
    u32 u2 = __float_as_uint(v2[0]);
    float s1 = __uint_as_float(u1 & 0xFFFFFC00u);
    float s2 = __uint_as_float(u2 & 0xFFFFFC00u);
    float ex = __expf((s2 - s1) * tsc);      // <= 1, stable
    float iw = 1.0f / (1.0f + ex);
    fw1[tl] = iw; fw2[tl] = ex * iw;
    fi1[tl] = (int)(u1 & 1023u); fi2[tl] = (int)(u2 & 1023u);
  }
  __syncthreads();

  // gather: token = tid>>1, dims [(tid&1)*32, +32)
  int tl = tid >> 1, d0 = (tid & 1) * 32;
  const float* va = V + ((size_t)h * 1024 + fi1[tl]) * 64 + d0;
  const float* vb = V + ((size_t)h * 1024 + fi2[tl]) * 64 + d0;
  float W1 = fw1[tl], W2 = fw2[tl];
  u16* dst = rd + (size_t)(t0 + tl) * 1024 + h * 64 + d0;
  #pragma unroll
  for (int g = 0; g < 4; ++g){
    f32x4 xa = *(const f32x4*)(va + g * 8);
    f32x4 xb = *(const f32x4*)(va + g * 8 + 4);
    f32x4 ya = *(const f32x4*)(vb + g * 8);
    f32x4 yb = *(const f32x4*)(vb + g * 8 + 4);
    uint4 o;
    o.x = (u32)f2bf(W1*xa[0]+W2*ya[0]) | ((u32)f2bf(W1*xa[1]+W2*ya[1]) << 16);
    o.y = (u32)f2bf(W1*xa[2]+W2*ya[2]) | ((u32)f2bf(W1*xa[3]+W2*ya[3]) << 16);
    o.z = (u32)f2bf(W1*xb[0]+W2*yb[0]) | ((u32)f2bf(W1*xb[1]+W2*yb[1]) << 16);
    o.w = (u32)f2bf(W1*xb[2]+W2*yb[2]) | ((u32)f2bf(W1*xb[3]+W2*yb[3]) << 16);
    *(uint4*)(dst + g * 8) = o;
  }
}

extern "C" void kernel_launch(void* const* d_in, const int* in_sizes, int n_in,
                              void* d_out, int out_size, void* d_ws, size_t ws_size,
                              hipStream_t stream){
  const float* x    = (const float*)d_in[0];
  const float* lng  = (const float*)d_in[1];
  const float* lnb  = (const float*)d_in[2];
  const float* qw   = (const float*)d_in[3];
  const float* qb   = (const float*)d_in[4];
  const float* sig  = (const float*)d_in[5];
  const float* sv   = (const float*)d_in[6];
  const float* ow   = (const float*)d_in[7];
  const float* ob   = (const float*)d_in[8];
  const float* temp = (const float*)d_in[9];
  float* out = (float*)d_out;

  char* ws = (char*)d_ws;
  u16* xn   = (u16*)(ws);                                  // 16 MiB  (x_norm bf16; reused as `read`)
  u16* qwb  = (u16*)(ws + 16777216);                       //  2 MiB
  u16* owb  = (u16*)(ws + 16777216 + 2097152);             //  2 MiB
  u16* sgb  = (u16*)(ws + 16777216 + 2 * 2097152);         //  2 MiB
  u16* qb16 = (u16*)(ws + 16777216 + 3 * 2097152);         // 16 MiB  (q bf16)
  u16* rdb  = xn;                                          // alias: x_norm dead after GEMM1

  convert_kernel<<<4096, 256, 0, stream>>>(qw, ow, sig, qwb, owb, sgb);
  ln_kernel<<<8192, 256, 0, stream>>>(x, lng, lnb, xn);
  gemm_bt<<<512, 256, 0, stream>>>(xn, qwb, qb, nullptr, nullptr, qb16, 0);
  route_kernel<<<dim3(64, 16), 256, 0, stream>>>(qb16, sgb, sv, temp, rdb);
  gemm_bt<<<512, 256, 0, stream>>>(rdb, owb, ob, x, out, nullptr, 1);
}

// Round 6
// 211.657 us; speedup vs baseline: 1.0279x; 1.0273x over previous
//
#include <hip/hip_runtime.h>

typedef unsigned short u16;
typedef unsigned int   u32;
typedef float f32x4  __attribute__((ext_vector_type(4)));
typedef float f32x16 __attribute__((ext_vector_type(16)));
typedef __bf16 bf16x8 __attribute__((ext_vector_type(8)));

__device__ __forceinline__ u16 f2bf(float f){
  u32 u = __float_as_uint(f);
  u += 0x7fffu + ((u >> 16) & 1u);          // RNE
  return (u16)(u >> 16);
}

// async global->LDS, 16B per lane; LDS dest is wave-uniform base + lane*16
__device__ __forceinline__ void gld16(const void* g, void* l){
  __builtin_amdgcn_global_load_lds((const __attribute__((address_space(1))) u32*)g,
                                   (__attribute__((address_space(3))) u32*)l, 16, 0, 0);
}

// ---------------- weight conversion: fp32->bf16, sigs->ternary bf16 ----------------
__global__ __launch_bounds__(256) void convert_kernel(
    const float* __restrict__ qw, const float* __restrict__ ow,
    const float* __restrict__ sg,
    u16* __restrict__ qwb, u16* __restrict__ owb, u16* __restrict__ sgb){
  int i = (blockIdx.x * 256 + threadIdx.x) * 4;   // 1,048,576 elements each
  f32x4 a = *(const f32x4*)(qw + i);
  f32x4 b = *(const f32x4*)(ow + i);
  f32x4 s = *(const f32x4*)(sg + i);
  uint2 pa, pb, ps;
  pa.x = (u32)f2bf(a[0]) | ((u32)f2bf(a[1]) << 16);
  pa.y = (u32)f2bf(a[2]) | ((u32)f2bf(a[3]) << 16);
  pb.x = (u32)f2bf(b[0]) | ((u32)f2bf(b[1]) << 16);
  pb.y = (u32)f2bf(b[2]) | ((u32)f2bf(b[3]) << 16);
  float t0 = (s[0] > 0.3f) ? 1.0f : ((s[0] < -0.3f) ? -1.0f : 0.0f);
  float t1 = (s[1] > 0.3f) ? 1.0f : ((s[1] < -0.3f) ? -1.0f : 0.0f);
  float t2 = (s[2] > 0.3f) ? 1.0f : ((s[2] < -0.3f) ? -1.0f : 0.0f);
  float t3 = (s[3] > 0.3f) ? 1.0f : ((s[3] < -0.3f) ? -1.0f : 0.0f);
  ps.x = (u32)f2bf(t0) | ((u32)f2bf(t1) << 16);
  ps.y = (u32)f2bf(t2) | ((u32)f2bf(t3) << 16);
  *(uint2*)(qwb + i) = pa;
  *(uint2*)(owb + i) = pb;
  *(uint2*)(sgb + i) = ps;
}

// ---------------- LayerNorm: one block per token ----------------
__global__ __launch_bounds__(256) void ln_kernel(
    const float* __restrict__ x, const float* __restrict__ g,
    const float* __restrict__ b, u16* __restrict__ xn){
  const int t = blockIdx.x, tid = threadIdx.x;
  f32x4 v = *(const f32x4*)(x + (size_t)t * 1024 + tid * 4);
  float s  = v[0] + v[1] + v[2] + v[3];
  float ss = v[0]*v[0] + v[1]*v[1] + v[2]*v[2] + v[3]*v[3];
  for (int off = 32; off; off >>= 1){
    s  += __shfl_down(s, off);
    ss += __shfl_down(ss, off);
  }
  __shared__ float red[8];
  int w = tid >> 6;
  if ((tid & 63) == 0){ red[w] = s; red[4 + w] = ss; }
  __syncthreads();
  s  = red[0] + red[1] + red[2] + red[3];
  ss = red[4] + red[5] + red[6] + red[7];
  float mean = s * (1.0f / 1024.0f);
  float var  = ss * (1.0f / 1024.0f) - mean * mean;   // jnp.var (ddof=0)
  float rs   = rsqrtf(var + 1e-5f);
  f32x4 gv = *(const f32x4*)(g + tid * 4);
  f32x4 bv = *(const f32x4*)(b + tid * 4);
  float y0 = (v[0]-mean)*rs*gv[0]+bv[0];
  float y1 = (v[1]-mean)*rs*gv[1]+bv[1];
  float y2 = (v[2]-mean)*rs*gv[2]+bv[2];
  float y3 = (v[3]-mean)*rs*gv[3]+bv[3];
  uint2 pk;
  pk.x = (u32)f2bf(y0) | ((u32)f2bf(y1) << 16);
  pk.y = (u32)f2bf(y2) | ((u32)f2bf(y3) << 16);
  *(uint2*)(xn + (size_t)t * 1024 + tid * 4) = pk;
}

// ---------------- bf16 MFMA GEMM: C[m,n] = sum_k A[m,k]*B[n,k] (+epilogue) ----------------
// M=8192, N=1024, K=1024. 128x128 tile, 4 waves in 2x2, each wave 64x64 (4x4 MFMA 16x16x32).
// Grid = 512 1-D, XCD-swizzled: XCD (b%8) owns a contiguous 1024-row A-stripe.
// LDS unpadded 64-u16 stride, XOR-swizzled: chunk g (16B) of row s at pos g^(s&7).
// mode 0: outb[m,n] = bf16(C + bias[n]);  mode 1: outf[m,n] = C + bias[n] + resid[m,n]
__global__ __launch_bounds__(256, 3) void gemm_bt(
    const u16* __restrict__ A, const u16* __restrict__ B,
    const float* __restrict__ bias, const float* __restrict__ resid,
    float* __restrict__ outf, u16* __restrict__ outb, int mode){
  __shared__ u16 As[128 * 64];      // 16 KB
  __shared__ u16 Bs[128 * 64];
  const int tid = threadIdx.x;
  const int b = blockIdx.x;
  const int m0 = ((b & 7) * 8 + ((b >> 3) & 7)) * 128;   // XCD-contiguous m-stripe
  const int n0 = (b >> 6) * 128;
  const int w = tid >> 6, lane = tid & 63, lm = lane & 15, quad = lane >> 4;
  const int wm = (w & 1) * 64, wn = (w >> 1) * 64;
  const int lr = lane >> 3;                 // row-within-8 of this lane's staging chunk
  const int lg = (lane & 7) ^ lr;           // swizzled source chunk id
  const f32x4 fz = {0.f, 0.f, 0.f, 0.f};
  f32x4 acc[4][4];
  #pragma unroll
  for (int i = 0; i < 4; ++i)
    #pragma unroll
    for (int j = 0; j < 4; ++j) acc[i][j] = fz;

  const u16* gA = A + (size_t)(m0 + w * 32 + lr) * 1024 + lg * 8;
  const u16* gB = B + (size_t)(n0 + w * 32 + lr) * 1024 + lg * 8;
  u16* lA = &As[(w * 32) * 64];             // wave-uniform LDS bases
  u16* lB = &Bs[(w * 32) * 64];
  const int sw = lm & 7;

  for (int kt = 0; kt < 16; ++kt){
    #pragma unroll
    for (int sub = 0; sub < 4; ++sub){
      gld16(gA + (size_t)(sub * 8) * 1024 + kt * 64, lA + sub * 8 * 64);
      gld16(gB + (size_t)(sub * 8) * 1024 + kt * 64, lB + sub * 8 * 64);
    }
    __syncthreads();
    #pragma unroll
    for (int kk = 0; kk < 2; ++kk){
      const int ch = ((quad + kk * 4) ^ sw) * 8;   // swizzled chunk offset (u16)
      bf16x8 afr[4], bfr[4];
      #pragma unroll
      for (int i = 0; i < 4; ++i)
        afr[i] = *(const bf16x8*)(&As[(wm + i * 16 + lm) * 64 + ch]);
      #pragma unroll
      for (int j = 0; j < 4; ++j)
        bfr[j] = *(const bf16x8*)(&Bs[(wn + j * 16 + lm) * 64 + ch]);
      #pragma unroll
      for (int i = 0; i < 4; ++i)
        #pragma unroll
        for (int j = 0; j < 4; ++j)
          acc[i][j] = __builtin_amdgcn_mfma_f32_16x16x32_bf16(afr[i], bfr[j], acc[i][j], 0, 0, 0);
    }
    __syncthreads();
  }

  #pragma unroll
  for (int i = 0; i < 4; ++i){
    #pragma unroll
    for (int r = 0; r < 4; ++r){
      int grow = m0 + wm + i * 16 + quad * 4 + r;
      #pragma unroll
      for (int j = 0; j < 4; ++j){
        int gcol = n0 + wn + j * 16 + lm;
        float v = acc[i][j][r] + bias[gcol];
        if (mode){
          v += resid[(size_t)grow * 1024 + gcol];
          outf[(size_t)grow * 1024 + gcol] = v;
        } else {
          outb[(size_t)grow * 1024 + gcol] = f2bf(v);
        }
      }
    }
  }
}

// ---------------- fused scores + top2 + softmax + gather ----------------
// block = 128 tokens x 1 head; 4 waves, wave w owns tokens [w*32, w*32+32).
// TRANSPOSED routing MFMA: sig = A operand (32 slots = rows), q = B operand
// (32 tokens = cols, loop-invariant fragments). Each lane's 16 acc elements
// are 16 slot-scores for ONE token -> running top-2 state is just 4 regs
// (v1,v2 keyed floats + b1,b2 block ids) -> nothing for the allocator to park
// in AGPRs (R3-R5: 32-reg state forced accvgpr churn, 4x VALU bloat).
// Key packing: low 5 mantissa bits hold slot-row-in-block (<=2^-18 rel);
// block id carried in a separate reg through a med3 tournament tree.
__global__ __launch_bounds__(256) void route_kernel(
    const u16* __restrict__ q, const u16* __restrict__ sig,
    const float* __restrict__ V, const float* __restrict__ temp,
    u16* __restrict__ rd){
  const int h = blockIdx.y;
  const int t0 = blockIdx.x * 128;
  const int tid = threadIdx.x, w = tid >> 6, lane = tid & 63;
  const int col = lane & 31, half = lane >> 5;

  __shared__ u16 sbuf[2][128 * 64];         // 2 x 16 KB, swizzled
  __shared__ float fw1[128], fw2[128];
  __shared__ int   fi1[128], fi2[128];

  // q B-fragments (loop-invariant): token n = t0+w*32+col; instr c: k = c*16+half*8+j
  const u16* qrow = q + (size_t)(t0 + w * 32 + col) * 1024 + h * 64 + half * 8;
  bf16x8 afr[4];
  #pragma unroll
  for (int c = 0; c < 4; ++c) afr[c] = *(const bf16x8*)(qrow + c * 16);

  const u16* sigh = sig + (size_t)h * 65536;

  // staging: wave w stages rows [w*32, w*32+32) of the 128-slot tile.
  // 8 lanes per row (16B chunks); swizzle: LDS pos p of row s holds chunk p^(s&7).
  const int lr = lane >> 3, lg = (lane & 7) ^ lr;
  const u16* ssrc = sigh + (size_t)(w * 32 + lr) * 64 + lg * 8;
  auto stage = [&](int t, int bb){
    const u16* s0 = ssrc + (size_t)t * 128 * 64;
    u16* d0 = &sbuf[bb][(w * 32) * 64];
    #pragma unroll
    for (int sub = 0; sub < 4; ++sub)
      gld16(s0 + sub * 8 * 64, d0 + sub * 8 * 64);
  };

  // loop-invariant swizzled read offsets (u16 units): sig instr c -> chunk 2c+half
  int p0 = ((0 + half) ^ (col & 7)) * 8;
  int p1 = ((2 + half) ^ (col & 7)) * 8;
  int p2 = ((4 + half) ^ (col & 7)) * 8;
  int p3 = ((6 + half) ^ (col & 7)) * 8;

  // rowkey table: acc[r] is slot-row (r&3)+8*(r>>2)+4*half within the 32-block
  u32 rk[16];
  #pragma unroll
  for (int r = 0; r < 16; ++r) rk[r] = (u32)((r & 3) + 8 * (r >> 2) + 4 * half);

  const f32x16 fzero = {};
  float v1 = -3.0e38f, v2 = -3.0e38f;
  u32 b1 = 0, b2 = 0;

  stage(0, 0);
  for (int t = 0; t < 8; ++t){
    __syncthreads();                         // drains vmcnt: staging of buf t&1 visible
    if (t < 7) stage(t + 1, (t + 1) & 1);
    const u16* buf = sbuf[t & 1];
    #pragma unroll
    for (int sbl = 0; sbl < 4; ++sbl){
      const u16* srow = &buf[(sbl * 32 + col) * 64];
      bf16x8 s0 = *(const bf16x8*)(srow + p0);
      bf16x8 s1 = *(const bf16x8*)(srow + p1);
      bf16x8 s2 = *(const bf16x8*)(srow + p2);
      bf16x8 s3 = *(const bf16x8*)(srow + p3);
      f32x16 acc;
      acc = __builtin_amdgcn_mfma_f32_32x32x16_bf16(s0, afr[0], fzero, 0, 0, 0);
      acc = __builtin_amdgcn_mfma_f32_32x32x16_bf16(s1, afr[1], acc, 0, 0, 0);
      acc = __builtin_amdgcn_mfma_f32_32x32x16_bf16(s2, afr[2], acc, 0, 0, 0);
      acc = __builtin_amdgcn_mfma_f32_32x32x16_bf16(s3, afr[3], acc, 0, 0, 0);
      // pack keys: masked score | slot-row-in-block
      float k[16];
      #pragma unroll
      for (int r = 0; r < 16; ++r)
        k[r] = __uint_as_float((__float_as_uint(acc[r]) & 0xFFFFFFE0u) | rk[r]);
      // tournament tree: top-2 of 16 keyed values
      float h1[8], h2[8];
      #pragma unroll
      for (int i = 0; i < 8; ++i){
        h1[i] = fmaxf(k[2*i], k[2*i+1]);
        h2[i] = fminf(k[2*i], k[2*i+1]);
      }
      float g1[4], g2[4];
      #pragma unroll
      for (int i = 0; i < 4; ++i){
        g1[i] = fmaxf(h1[2*i], h1[2*i+1]);
        g2[i] = __builtin_amdgcn_fmed3f(h1[2*i], h1[2*i+1], fmaxf(h2[2*i], h2[2*i+1]));
      }
      float e1[2], e2[2];
      #pragma unroll
      for (int i = 0; i < 2; ++i){
        e1[i] = fmaxf(g1[2*i], g1[2*i+1]);
        e2[i] = __builtin_amdgcn_fmed3f(g1[2*i], g1[2*i+1], fmaxf(g2[2*i], g2[2*i+1]));
      }
      float m1 = fmaxf(e1[0], e1[1]);
      float m2 = __builtin_amdgcn_fmed3f(e1[0], e1[1], fmaxf(e2[0], e2[1]));
      // merge block top-2 into running (block id bt rides in b1/b2)
      u32 bt = (u32)(t * 4 + sbl);
      u32   cb2 = (m2 > v2) ? bt : b2;
      float c2  = fmaxf(v2, m2);
      u32   nb1 = (m1 > v1) ? bt : b1;
      float n1  = fmaxf(v1, m1);
      float n2  = __builtin_amdgcn_fmed3f(v1, m1, c2);
      u32   nb2 = (n2 == m1) ? bt : ((n2 == v1) ? b1 : cb2);
      v1 = n1; b1 = nb1; v2 = n2; b2 = nb2;
    }
  }

  // cross-half merge: lanes col and col+32 hold complementary slot rows of the
  // same token (rowkey includes 4*half -> keys can never collide on one slot)
  {
    float o1 = __shfl_xor(v1, 32);
    float o2 = __shfl_xor(v2, 32);
    u32 ob1 = (u32)__shfl_xor((int)b1, 32);
    u32 ob2 = (u32)__shfl_xor((int)b2, 32);
    u32   cb2 = (o2 > v2) ? ob2 : b2;
    float c2  = fmaxf(v2, o2);
    u32   nb1 = (o1 > v1) ? ob1 : b1;
    float n1  = fmaxf(v1, o1);
    float n2  = __builtin_amdgcn_fmed3f(v1, o1, c2);
    u32   nb2 = (n2 == o1) ? ob1 : ((n2 == v1) ? b1 : cb2);
    v1 = n1; b1 = nb1; v2 = n2; b2 = nb2;
  }

  if (half == 0){
    int tl = w * 32 + col;
    u32 u1 = __float_as_uint(v1);
    u32 u2 = __float_as_uint(v2);
    float s1 = __uint_as_float(u1 & 0xFFFFFFE0u);
    float s2 = __uint_as_float(u2 & 0xFFFFFFE0u);
    float tsc = 1.0f / (temp[0] * 8.0f);     // 1/(temperature*sqrt(64))
    float ex = __expf((s2 - s1) * tsc);      // <= 1, stable
    float iw = 1.0f / (1.0f + ex);
    fw1[tl] = iw; fw2[tl] = ex * iw;
    fi1[tl] = (int)(b1 * 32 + (u1 & 31u));
    fi2[tl] = (int)(b2 * 32 + (u2 & 31u));
  }
  __syncthreads();

  // gather: token = tid>>1, dims [(tid&1)*32, +32)
  int tl = tid >> 1, d0 = (tid & 1) * 32;
  const float* va = V + ((size_t)h * 1024 + fi1[tl]) * 64 + d0;
  const float* vb = V + ((size_t)h * 1024 + fi2[tl]) * 64 + d0;
  float W1 = fw1[tl], W2 = fw2[tl];
  u16* dst = rd + (size_t)(t0 + tl) * 1024 + h * 64 + d0;
  #pragma unroll
  for (int g = 0; g < 4; ++g){
    f32x4 xa = *(const f32x4*)(va + g * 8);
    f32x4 xb = *(const f32x4*)(va + g * 8 + 4);
    f32x4 ya = *(const f32x4*)(vb + g * 8);
    f32x4 yb = *(const f32x4*)(vb + g * 8 + 4);
    uint4 o;
    o.x = (u32)f2bf(W1*xa[0]+W2*ya[0]) | ((u32)f2bf(W1*xa[1]+W2*ya[1]) << 16);
    o.y = (u32)f2bf(W1*xa[2]+W2*ya[2]) | ((u32)f2bf(W1*xa[3]+W2*ya[3]) << 16);
    o.z = (u32)f2bf(W1*xb[0]+W2*yb[0]) | ((u32)f2bf(W1*xb[1]+W2*yb[1]) << 16);
    o.w = (u32)f2bf(W1*xb[2]+W2*yb[2]) | ((u32)f2bf(W1*xb[3]+W2*yb[3]) << 16);
    *(uint4*)(dst + g * 8) = o;
  }
}

extern "C" void kernel_launch(void* const* d_in, const int* in_sizes, int n_in,
                              void* d_out, int out_size, void* d_ws, size_t ws_size,
                              hipStream_t stream){
  const float* x    = (const float*)d_in[0];
  const float* lng  = (const float*)d_in[1];
  const float* lnb  = (const float*)d_in[2];
  const float* qw   = (const float*)d_in[3];
  const float* qb   = (const float*)d_in[4];
  const float* sig  = (const float*)d_in[5];
  const float* sv   = (const float*)d_in[6];
  const float* ow   = (const float*)d_in[7];
  const float* ob   = (const float*)d_in[8];
  const float* temp = (const float*)d_in[9];
  float* out = (float*)d_out;

  char* ws = (char*)d_ws;
  u16* xn   = (u16*)(ws);                                  // 16 MiB  (x_norm bf16; reused as `read`)
  u16* qwb  = (u16*)(ws + 16777216);                       //  2 MiB
  u16* owb  = (u16*)(ws + 16777216 + 2097152);             //  2 MiB
  u16* sgb  = (u16*)(ws + 16777216 + 2 * 2097152);         //  2 MiB
  u16* qb16 = (u16*)(ws + 16777216 + 3 * 2097152);         // 16 MiB  (q bf16)
  u16* rdb  = xn;                                          // alias: x_norm dead after GEMM1

  convert_kernel<<<1024, 256, 0, stream>>>(qw, ow, sig, qwb, owb, sgb);
  ln_kernel<<<8192, 256, 0, stream>>>(x, lng, lnb, xn);
  gemm_bt<<<512, 256, 0, stream>>>(xn, qwb, qb, nullptr, nullptr, qb16, 0);
  route_kernel<<<dim3(64, 16), 256, 0, stream>>>(qb16, sgb, sv, temp, rdb);
  gemm_bt<<<512, 256, 0, stream>>>(rdb, owb, ob, x, out, nullptr, 1);
}